// Round 5
// baseline (147.985 us; speedup 1.0000x reference)
//
#include <hip/hip_runtime.h>
#include <hip/hip_bf16.h>

// RuleNBFNet: B=8, D=64, H=3, R2=12, Rn=1728.  Inputs f32, output f32.
// Decomposition (hidden level m depends only on rule components 0..m-1):
//   P1[b,i0]   = level1 after layer0          (96 vecs)
//   C2         = level2/3 after layer0 (constant vec)
//   Q2[b,i0,i1]= level2 after layer1          (1152 vecs)
//   Q3[b,i2]   = level3 after layer1          (96 vecs)
//   final[b,r] = level3 after layer2 -> fused into MLP score (13824 instances)
// Level-0 path (upd0/scales_head) never reaches the output (only h3 is read).
// mlp_b2 is softmax-invariant -> dropped.
// upd@W refactor: Wt[l][d][j][c] = sum_s scales_tail[s]*lin_W[l][64+12d+3c+s, j]
//   scales_tail = [1, 4/3, 3/4]; c=0 column pre-scaled by 0.5 (mean term).
// std identity: sqrt(max(0.25 m^2, eps)) == max(0.5|m|, 1e-3)  (exact).

typedef const float* fp;

// workspace layout (floats)
#define WS_WT     0        // 3*64*64*4 = 49152   Wt[l][d][j][c]
#define WS_RELT   49152    // 3*8*12*64 = 18432   relT[l][b][j][d]
#define WS_QW1    67584    // 8*64                query@mlp_W1[64:128]+mlp_b1
#define WS_C2     68096    // 64
#define WS_C2W    68160    // 64                  C2@lin_W1[0:64] + lin_b1
#define WS_P1     68224    // 8*12*64
#define WS_Q3     74368    // 8*12*64
#define WS_Q2     80512    // 8*144*64
#define WS_QW3    154240   // 8*12*64             Q3@lin_W2[0:64] + lin_b2
#define WS_SCORES 160384   // 8*1728
// total 174208 floats = 696832 bytes

__global__ void k_pre1(fp lin_W, fp query, fp rel_W, fp rel_b, fp mlp_W1,
                       fp mlp_b1, float* ws){
  int t = blockIdx.x*256 + threadIdx.x;
  if (t < 49152){
    // Wt[l][d][j][c]: t = l*16384 + d*256 + j*4 + c  (coalesced writes)
    int c = t & 3; int j = (t>>2)&63; int d = (t>>8)&63; int l = t>>14;
    int row = 64 + 12*d + 3*c;
    fp W = lin_W + (size_t)l*832*64;
    float v = W[row*64+j] + (4.0f/3.0f)*W[(row+1)*64+j] + 0.75f*W[(row+2)*64+j];
    if (c == 0) v *= 0.5f;            // fold mean's 0.5
    ws[WS_WT + t] = v;
  } else if (t < 67584){
    // relT[l][b][j][d] = (query[b] @ rel_W[l])[j*64+d] + rel_b[l][j*64+d]
    int e = t - 49152;
    int d = e & 63; int j = (e>>6)%12; int b = (e/768)&7; int l = e/6144;
    float acc = rel_b[l*768 + j*64 + d];
    fp W = rel_W + (size_t)l*64*768 + j*64 + d;
    fp q = query + b*64;
    for (int k=0;k<64;k++) acc += q[k] * W[k*768];
    ws[WS_RELT + e] = acc;
  } else if (t < 68096){
    int e = t - 67584; int b = e>>6; int j = e&63;
    float acc = mlp_b1[j];
    fp q = query + b*64;
    for (int i=0;i<64;i++) acc += q[i] * mlp_W1[(64+i)*64 + j];
    ws[WS_QW1 + e] = acc;
  }
}

__global__ void k_pre2(fp lin_W, fp lin_b, float* ws){
  __shared__ float sC2[64];
  int j = threadIdx.x;
  float acc = lin_b[j];                            // layer0 bias
  for (int d=0; d<64; d++) acc += 1e-3f * ws[WS_WT + ((d<<6)+j)*4 + 3];
  float c2 = fmaxf(acc, 0.0f);
  ws[WS_C2 + j] = c2; sC2[j] = c2;
  __syncthreads();
  float a2 = lin_b[64+j];                          // layer1 bias
  fp W1 = lin_W + 832*64;                          // layer1, rows 0..63
  for (int k=0;k<64;k++) a2 += sC2[k] * W1[k*64+j];
  ws[WS_C2W + j] = a2;
}

__global__ void k_pre3(fp indicator, fp lin_b, float* ws){
  int wave = blockIdx.x*4 + (threadIdx.x>>6);      // 0..191
  int j = threadIdx.x & 63;
  bool isP = wave < 96;
  int e = isP ? wave : wave - 96;
  int b = e/12, ii = e%12;
  const float* Wl  = ws + WS_WT + (isP ? 0 : 16384);
  const float* rel = ws + WS_RELT + (isP ? 0 : 6144) + (b*12+ii)*64;
  float acc = isP ? lin_b[j] : ws[WS_C2W + j];
  for (int d=0; d<64; d++){
    float src = isP ? indicator[d] : ws[WS_C2 + d];
    float m = src * rel[d];
    float4 wv = *(const float4*)(Wl + ((d<<6)+j)*4);
    acc += m*wv.x + fmaxf(m,0.f)*wv.y + fminf(m,0.f)*wv.z
         + fmaxf(0.5f*fabsf(m),1e-3f)*wv.w;
  }
  float* outp = ws + (isP ? WS_P1 : WS_Q3) + e*64 + j;
  *outp = fmaxf(acc, 0.f);
}

__global__ void k_pre4(fp lin_W, fp lin_b, float* ws){
  int wave = blockIdx.x*4 + (threadIdx.x>>6);      // 0..1247
  int j = threadIdx.x & 63;
  if (wave < 1152){
    int b = wave/144, i0 = (wave/12)%12, i1 = wave%12;
    const float* p   = ws + WS_P1 + (b*12+i0)*64;
    const float* rel = ws + WS_RELT + 6144 + (b*12+i1)*64;
    const float* Wt1 = ws + WS_WT + 16384;
    float acc = ws[WS_C2W + j];
    for (int d=0; d<64; d++){
      float m = p[d]*rel[d];
      float4 wv = *(const float4*)(Wt1 + ((d<<6)+j)*4);
      acc += m*wv.x + fmaxf(m,0.f)*wv.y + fminf(m,0.f)*wv.z
           + fmaxf(0.5f*fabsf(m),1e-3f)*wv.w;
    }
    ws[WS_Q2 + wave*64 + j] = fmaxf(acc, 0.f);
  } else if (wave < 1248){
    int e = wave - 1152;
    const float* q = ws + WS_Q3 + e*64;
    fp W2 = lin_W + 2*832*64;                      // layer2, rows 0..63
    float acc = lin_b[128 + j];
    for (int k=0;k<64;k++) acc += q[k]*W2[k*64+j];
    ws[WS_QW3 + e*64 + j] = acc;
  }
}

// one wave = 4 rules sharing (b,i0,i2), i1 in {i1b..i1b+3}: Wt2 regs reused 4x
__global__ __launch_bounds__(256) void k_score(fp mlp_W1, fp mlp_W2, float* ws){
  __shared__ float fin[4][4][64];
  int w = threadIdx.x >> 6;
  int j = threadIdx.x & 63;
  int wave = blockIdx.x*4 + w;                 // 0..3455
  int b = wave/432; int rem = wave%432;
  int i0 = rem/36; int t36 = rem%36;
  int i2 = t36/3;  int i1b = (t36%3)*4;
  const float* Wt2    = ws + WS_WT + 32768;
  const float* rel    = ws + WS_RELT + 12288 + (b*12+i2)*64;
  const float* q2base = ws + WS_Q2 + ((b*12+i0)*12 + i1b)*64;
  float a0 = ws[WS_QW3 + (b*12+i2)*64 + j];
  float acc0=a0, acc1=a0, acc2=a0, acc3=a0;
  for (int d=0; d<64; d++){
    float rv = rel[d];
    float4 wv = *(const float4*)(Wt2 + ((d<<6)+j)*4);
    float m0 = q2base[d]      *rv;
    float m1 = q2base[64+d]   *rv;
    float m2 = q2base[128+d]  *rv;
    float m3 = q2base[192+d]  *rv;
    acc0 += m0*wv.x + fmaxf(m0,0.f)*wv.y + fminf(m0,0.f)*wv.z + fmaxf(0.5f*fabsf(m0),1e-3f)*wv.w;
    acc1 += m1*wv.x + fmaxf(m1,0.f)*wv.y + fminf(m1,0.f)*wv.z + fmaxf(0.5f*fabsf(m1),1e-3f)*wv.w;
    acc2 += m2*wv.x + fmaxf(m2,0.f)*wv.y + fminf(m2,0.f)*wv.z + fmaxf(0.5f*fabsf(m2),1e-3f)*wv.w;
    acc3 += m3*wv.x + fmaxf(m3,0.f)*wv.y + fminf(m3,0.f)*wv.z + fmaxf(0.5f*fabsf(m3),1e-3f)*wv.w;
  }
  fin[w][0][j]=fmaxf(acc0,0.f); fin[w][1][j]=fmaxf(acc1,0.f);
  fin[w][2][j]=fmaxf(acc2,0.f); fin[w][3][j]=fmaxf(acc3,0.f);
  __syncthreads();
  float qw = ws[WS_QW1 + b*64 + j];
  float w2 = mlp_W2[j];
  for (int g=0; g<4; g++){
    float h = qw;
    const float* f = fin[w][g];
    for (int i=0;i<64;i++) h += f[i]*mlp_W1[i*64+j];   // rows 0..63
    h = fmaxf(h, 0.f);
    float s = h * w2;
    for (int off=32; off>0; off>>=1) s += __shfl_down(s, off, 64);
    if (j == 0){
      int r = i0*144 + (i1b+g)*12 + i2;
      ws[WS_SCORES + b*1728 + r] = s;          // mlp_b2 dropped (softmax-inv)
    }
  }
}

__global__ void k_final(fp relation_emb, float* ws, float* out){
  const float* sc = ws + WS_SCORES + blockIdx.x*1728;
  int b = blockIdx.x, tid = threadIdx.x;
  __shared__ float red[256];
  __shared__ float bins[3][12];
  float mx = -1e30f;
  for (int r=tid; r<1728; r+=256) mx = fmaxf(mx, sc[r]);
  red[tid] = mx; __syncthreads();
  for (int s=128; s>0; s>>=1){ if (tid<s) red[tid] = fmaxf(red[tid], red[tid+s]); __syncthreads(); }
  mx = red[0];
  __syncthreads();
  if (tid < 36) ((float*)bins)[tid] = 0.f;
  __syncthreads();
  float tsum = 0.f;
  for (int r=tid; r<1728; r+=256){
    float e = expf(sc[r]-mx);
    tsum += e;
    atomicAdd(&bins[0][r/144], e);
    atomicAdd(&bins[1][(r/12)%12], e);
    atomicAdd(&bins[2][r%12], e);
  }
  red[tid] = tsum; __syncthreads();
  for (int s=128; s>0; s>>=1){ if (tid<s) red[tid] += red[tid+s]; __syncthreads(); }
  float tot = red[0];
  if (tid < 192){
    int h = tid/64, d = tid%64;
    float acc = 0.f;
    for (int jj=0; jj<12; jj++) acc += bins[h][jj] * relation_emb[jj*64+d];
    out[b*192 + tid] = acc/tot;                      // subgoals, f32
  }
  if (tid >= 192 && tid < 195){
    out[1536 + b*3 + (tid-192)] = 1.0f;              // masks = True, f32
  }
}

extern "C" void kernel_launch(void* const* d_in, const int* in_sizes, int n_in,
                              void* d_out, int out_size, void* d_ws, size_t ws_size,
                              hipStream_t stream){
  fp query        = (fp)d_in[0];
  fp relation_emb = (fp)d_in[1];
  fp indicator    = (fp)d_in[2];
  fp rel_W        = (fp)d_in[3];
  fp rel_b        = (fp)d_in[4];
  fp lin_W        = (fp)d_in[5];
  fp lin_b        = (fp)d_in[6];
  fp mlp_W1       = (fp)d_in[7];
  fp mlp_b1       = (fp)d_in[8];
  fp mlp_W2       = (fp)d_in[9];
  float* ws = (float*)d_ws;
  float* out = (float*)d_out;

  k_pre1 <<<266, 256, 0, stream>>>(lin_W, query, rel_W, rel_b, mlp_W1, mlp_b1, ws);
  k_pre2 <<<1,    64, 0, stream>>>(lin_W, lin_b, ws);
  k_pre3 <<<48,  256, 0, stream>>>(indicator, lin_b, ws);
  k_pre4 <<<312, 256, 0, stream>>>(lin_W, lin_b, ws);
  k_score<<<864, 256, 0, stream>>>(mlp_W1, mlp_W2, ws);
  k_final<<<8,   256, 0, stream>>>(relation_emb, ws, out);
}

// Round 6
// 136.816 us; speedup vs baseline: 1.0816x; 1.0816x over previous
//
#include <hip/hip_runtime.h>
#include <hip/hip_bf16.h>

// RuleNBFNet: B=8, D=64, H=3, R2=12, Rn=1728.  Inputs f32, output f32.
// Decomposition (hidden level m depends only on rule components 0..m-1):
//   P1[b,i0], C2 (const), Q2[b,i0,i1], Q3[b,i2], final fused into MLP score.
// Feature algebra: with m=q*rel, p=max(m,0), n=min(m,0):
//   0.5m*W0 + p*W1 + n*W2 + max(0.5|m|,1e-3)*W3
//     = p*A + n*Bc + max(0.5|m|,1e-3)*Wz,  A=0.5W0+W1, Bc=0.5W0+W2, Wz=W3
// where Wk[d][j] = sum_s scales_tail[s]*lin_W[64+12d+3k+s, j], scales=[1,4/3,3/4].
// Wt layout: float4 (A, Bc, Wz, 0) at [l][d][j].
// std identity: sqrt(max(0.25 m^2, eps)) == max(0.5|m|, 1e-3)  (exact).
// mlp_b2 softmax-invariant -> dropped.

typedef const float* fp;

// workspace layout (floats)
#define WS_WT     0        // 3*64*64*4 = 49152   Wt[l][d][j][c]
#define WS_RELT   49152    // 3*8*12*64 = 18432   relT[l][b][j][d]
#define WS_QW1    67584    // 8*64                query@mlp_W1[64:128]+mlp_b1
#define WS_C2     68096    // 64
#define WS_C2W    68160    // 64                  C2@lin_W1[0:64] + lin_b1
#define WS_P1     68224    // 8*12*64
#define WS_Q3     74368    // 8*12*64
#define WS_Q2     80512    // 8*144*64
#define WS_QW3    154240   // 8*12*64             Q3@lin_W2[0:64] + lin_b2
#define WS_SCORES 160384   // 8*1728
// total 174208 floats = 696832 bytes

__device__ __forceinline__ void acc4f(float q, float rv, float4 wv, float& acc){
  float m = q*rv;
  float p = fmaxf(m, 0.f), n = fminf(m, 0.f);
  acc += p*wv.x;
  acc += n*wv.y;
  acc += fmaxf(0.5f*fabsf(m), 1e-3f)*wv.z;
}

__global__ void k_pre1(fp lin_W, fp query, fp rel_W, fp rel_b, fp mlp_W1,
                       fp mlp_b1, float* ws){
  int t = blockIdx.x*256 + threadIdx.x;
  if (t < 49152){
    // Wt[l][d][j][c]: t = l*16384 + d*256 + j*4 + c  (coalesced writes)
    int c = t & 3; int j = (t>>2)&63; int d = (t>>8)&63; int l = t>>14;
    fp W = lin_W + (size_t)l*832*64 + (64 + 12*d)*64 + j;   // rows stride 64
    float v = 0.f;
    if (c == 0){
      float w0 = W[0] + (4.f/3.f)*W[64]  + 0.75f*W[128];
      float w1 = W[192] + (4.f/3.f)*W[256] + 0.75f*W[320];
      v = 0.5f*w0 + w1;
    } else if (c == 1){
      float w0 = W[0] + (4.f/3.f)*W[64]  + 0.75f*W[128];
      float w2 = W[384] + (4.f/3.f)*W[448] + 0.75f*W[512];
      v = 0.5f*w0 + w2;
    } else if (c == 2){
      v = W[576] + (4.f/3.f)*W[640] + 0.75f*W[704];
    }
    ws[WS_WT + t] = v;
  } else if (t < 67584){
    // relT[l][b][j][d] = (query[b] @ rel_W[l])[j*64+d] + rel_b[l][j*64+d]
    int e = t - 49152;
    int d = e & 63; int j = (e>>6)%12; int b = (e/768)&7; int l = e/6144;
    float acc = rel_b[l*768 + j*64 + d];
    fp W = rel_W + (size_t)l*64*768 + j*64 + d;
    fp q = query + b*64;
    #pragma unroll 8
    for (int k=0;k<64;k++) acc += q[k] * W[k*768];
    ws[WS_RELT + e] = acc;
  } else if (t < 68096){
    int e = t - 67584; int b = e>>6; int j = e&63;
    float acc = mlp_b1[j];
    fp q = query + b*64;
    #pragma unroll 8
    for (int i=0;i<64;i++) acc += q[i] * mlp_W1[(64+i)*64 + j];
    ws[WS_QW1 + e] = acc;
  }
}

// P1 + Q3; C2/C2W computed inline per block (tiny), block 0 publishes C2W.
__global__ void k_pre3(fp indicator, fp lin_W, fp lin_b, float* ws){
  __shared__ float sC2[64], sC2W[64];
  int tid = threadIdx.x;
  if (tid < 64){
    int j = tid;
    float acc = lin_b[j];                          // layer0 bias
    #pragma unroll 8
    for (int d=0; d<64; d++) acc += 1e-3f * ws[WS_WT + ((d<<6)+j)*4 + 2];
    sC2[j] = fmaxf(acc, 0.f);
  }
  __syncthreads();
  if (tid < 64){
    int j = tid;
    float a2 = lin_b[64+j];                        // layer1 bias
    fp W1 = lin_W + 832*64;                        // layer1, rows 0..63
    #pragma unroll 8
    for (int k=0;k<64;k++) a2 += sC2[k] * W1[k*64+j];
    sC2W[j] = a2;
    if (blockIdx.x == 0){ ws[WS_C2 + j] = sC2[j]; ws[WS_C2W + j] = a2; }
  }
  __syncthreads();

  int wave = blockIdx.x*4 + (tid>>6);              // 0..191
  int j = tid & 63;
  bool isP = wave < 96;
  int e = isP ? wave : wave - 96;
  int b = e/12, ii = e%12;
  const float4* W4 = (const float4*)(ws + WS_WT + (isP ? 0 : 16384));
  const float* rel = ws + WS_RELT + (isP ? 0 : 6144) + (b*12+ii)*64;
  float acc = isP ? lin_b[j] : sC2W[j];
  #pragma unroll 4
  for (int d=0; d<64; d++){
    float src = isP ? indicator[d] : sC2[d];
    float4 wv = W4[(d<<6)+j];
    acc4f(src, rel[d], wv, acc);
  }
  float* outp = ws + (isP ? WS_P1 : WS_Q3) + e*64 + j;
  *outp = fmaxf(acc, 0.f);
}

__global__ void k_pre4(fp lin_W, fp lin_b, float* ws){
  int wave = blockIdx.x*4 + (threadIdx.x>>6);      // 0..1247
  int j = threadIdx.x & 63;
  if (wave < 1152){
    int b = wave/144, i0 = (wave/12)%12, i1 = wave%12;
    const float4* pv   = (const float4*)(ws + WS_P1 + (b*12+i0)*64);
    const float4* relv = (const float4*)(ws + WS_RELT + 6144 + (b*12+i1)*64);
    const float4* W4j  = (const float4*)(ws + WS_WT + 16384) + j;
    float acc = ws[WS_C2W + j];
    #pragma unroll 4
    for (int dc=0; dc<16; dc++){
      float4 rv = relv[dc];
      float4 p  = pv[dc];
      float4 w0 = W4j[(4*dc+0)*64];
      float4 w1 = W4j[(4*dc+1)*64];
      float4 w2 = W4j[(4*dc+2)*64];
      float4 w3 = W4j[(4*dc+3)*64];
      acc4f(p.x, rv.x, w0, acc);
      acc4f(p.y, rv.y, w1, acc);
      acc4f(p.z, rv.z, w2, acc);
      acc4f(p.w, rv.w, w3, acc);
    }
    ws[WS_Q2 + wave*64 + j] = fmaxf(acc, 0.f);
  } else if (wave < 1248){
    int e = wave - 1152;
    const float* q = ws + WS_Q3 + e*64;
    fp W2 = lin_W + 2*832*64;                      // layer2, rows 0..63
    float acc = lin_b[128 + j];
    #pragma unroll 8
    for (int k=0;k<64;k++) acc += q[k]*W2[k*64+j];
    ws[WS_QW3 + e*64 + j] = acc;
  }
}

// one wave = 4 rules sharing (b,i0,i2), i1 in {i1b..i1b+3}: Wt2 loads reused 4x
__global__ __launch_bounds__(256, 4) void k_score(fp mlp_W1, fp mlp_W2, float* ws){
  __shared__ float fin[4][4][64];
  int w = threadIdx.x >> 6;
  int j = threadIdx.x & 63;
  int wave = blockIdx.x*4 + w;                 // 0..3455
  int b = wave/432; int rem = wave%432;
  int i0 = rem/36; int t36 = rem%36;
  int i2 = t36/3;  int i1b = (t36%3)*4;
  const float4* W4j  = (const float4*)(ws + WS_WT + 32768) + j;
  const float4* relv = (const float4*)(ws + WS_RELT + 12288 + (b*12+i2)*64);
  const float* q2base = ws + WS_Q2 + ((b*12+i0)*12 + i1b)*64;
  const float4* q0v = (const float4*)(q2base);
  const float4* q1v = (const float4*)(q2base + 64);
  const float4* q2v = (const float4*)(q2base + 128);
  const float4* q3v = (const float4*)(q2base + 192);
  float a0 = ws[WS_QW3 + (b*12+i2)*64 + j];
  float acc0=a0, acc1=a0, acc2=a0, acc3=a0;
  #pragma unroll 4
  for (int dc=0; dc<16; dc++){
    float4 rv = relv[dc];
    float4 qa = q0v[dc], qb = q1v[dc], qc = q2v[dc], qd = q3v[dc];
    float4 w0 = W4j[(4*dc+0)*64];
    float4 w1 = W4j[(4*dc+1)*64];
    float4 w2 = W4j[(4*dc+2)*64];
    float4 w3 = W4j[(4*dc+3)*64];
    acc4f(qa.x, rv.x, w0, acc0); acc4f(qb.x, rv.x, w0, acc1);
    acc4f(qc.x, rv.x, w0, acc2); acc4f(qd.x, rv.x, w0, acc3);
    acc4f(qa.y, rv.y, w1, acc0); acc4f(qb.y, rv.y, w1, acc1);
    acc4f(qc.y, rv.y, w1, acc2); acc4f(qd.y, rv.y, w1, acc3);
    acc4f(qa.z, rv.z, w2, acc0); acc4f(qb.z, rv.z, w2, acc1);
    acc4f(qc.z, rv.z, w2, acc2); acc4f(qd.z, rv.z, w2, acc3);
    acc4f(qa.w, rv.w, w3, acc0); acc4f(qb.w, rv.w, w3, acc1);
    acc4f(qc.w, rv.w, w3, acc2); acc4f(qd.w, rv.w, w3, acc3);
  }
  fin[w][0][j]=fmaxf(acc0,0.f); fin[w][1][j]=fmaxf(acc1,0.f);
  fin[w][2][j]=fmaxf(acc2,0.f); fin[w][3][j]=fmaxf(acc3,0.f);
  __syncthreads();
  float qw = ws[WS_QW1 + b*64 + j];
  float w2 = mlp_W2[j];
  for (int g=0; g<4; g++){
    float h = qw;
    const float* f = fin[w][g];
    #pragma unroll 8
    for (int i=0;i<64;i++) h += f[i]*mlp_W1[i*64+j];   // rows 0..63
    h = fmaxf(h, 0.f);
    float s = h * w2;
    for (int off=32; off>0; off>>=1) s += __shfl_down(s, off, 64);
    if (j == 0){
      int r = i0*144 + (i1b+g)*12 + i2;
      ws[WS_SCORES + b*1728 + r] = s;          // mlp_b2 dropped (softmax-inv)
    }
  }
}

__global__ void k_final(fp relation_emb, float* ws, float* out){
  int b = blockIdx.x, tid = threadIdx.x;           // 256 threads
  __shared__ float se[1728];
  __shared__ float red[256];
  __shared__ float bins[36];
  const float* sc = ws + WS_SCORES + b*1728;
  float mx = -1e30f;
  for (int r=tid; r<1728; r+=256){ float v = sc[r]; se[r] = v; mx = fmaxf(mx, v); }
  red[tid] = mx; __syncthreads();
  for (int s=128; s>0; s>>=1){ if (tid<s) red[tid] = fmaxf(red[tid], red[tid+s]); __syncthreads(); }
  mx = red[0]; __syncthreads();
  float ts = 0.f;
  for (int r=tid; r<1728; r+=256){ float e = expf(se[r]-mx); se[r] = e; ts += e; }
  red[tid] = ts; __syncthreads();
  for (int s=128; s>0; s>>=1){ if (tid<s) red[tid] += red[tid+s]; __syncthreads(); }
  float tot = red[0]; __syncthreads();
  if (tid < 36){
    int h = tid/12, jj = tid%12;
    float a = 0.f;
    if (h == 0){
      const float* p = se + jj*144;
      for (int k=0;k<144;k++) a += p[k];
    } else if (h == 1){
      for (int i0=0;i0<12;i0++){
        const float* p = se + i0*144 + jj*12;
        for (int i2=0;i2<12;i2++) a += p[i2];
      }
    } else {
      for (int i0=0;i0<12;i0++)
        for (int i1=0;i1<12;i1++) a += se[i0*144 + i1*12 + jj];
    }
    bins[tid] = a;
  }
  __syncthreads();
  if (tid < 192){
    int h = tid>>6, d = tid&63;
    float acc = 0.f;
    #pragma unroll
    for (int jj=0; jj<12; jj++) acc += bins[h*12+jj] * relation_emb[jj*64+d];
    out[b*192 + tid] = acc/tot;                    // subgoals, f32
  }
  if (tid >= 192 && tid < 195){
    out[1536 + b*3 + (tid-192)] = 1.0f;            // masks = True, f32
  }
}

extern "C" void kernel_launch(void* const* d_in, const int* in_sizes, int n_in,
                              void* d_out, int out_size, void* d_ws, size_t ws_size,
                              hipStream_t stream){
  fp query        = (fp)d_in[0];
  fp relation_emb = (fp)d_in[1];
  fp indicator    = (fp)d_in[2];
  fp rel_W        = (fp)d_in[3];
  fp rel_b        = (fp)d_in[4];
  fp lin_W        = (fp)d_in[5];
  fp lin_b        = (fp)d_in[6];
  fp mlp_W1       = (fp)d_in[7];
  fp mlp_b1       = (fp)d_in[8];
  fp mlp_W2       = (fp)d_in[9];
  float* ws = (float*)d_ws;
  float* out = (float*)d_out;

  k_pre1 <<<266, 256, 0, stream>>>(lin_W, query, rel_W, rel_b, mlp_W1, mlp_b1, ws);
  k_pre3 <<<48,  256, 0, stream>>>(indicator, lin_W, lin_b, ws);
  k_pre4 <<<312, 256, 0, stream>>>(lin_W, lin_b, ws);
  k_score<<<864, 256, 0, stream>>>(mlp_W1, mlp_W2, ws);
  k_final<<<8,   256, 0, stream>>>(relation_emb, ws, out);
}

// Round 7
// 136.794 us; speedup vs baseline: 1.0818x; 1.0002x over previous
//
#include <hip/hip_runtime.h>
#include <hip/hip_bf16.h>

// RuleNBFNet: B=8, D=64, H=3, R2=12, Rn=1728.  Inputs f32, output f32.
// Decomposition (hidden level m depends only on rule components 0..m-1):
//   P1[b,i0], C2 (const), Q2[b,i0,i1], Q3[b,i2], final fused into MLP score.
// Feature algebra: with m=q*rel, p=max(m,0), n=min(m,0):
//   0.5m*W0 + p*W1 + n*W2 + max(0.5|m|,1e-3)*W3
//     = p*A + n*Bc + max(0.5|m|,1e-3)*Wz,  A=0.5W0+W1, Bc=0.5W0+W2, Wz=W3
// where Wk[d][j] = sum_s scales_tail[s]*lin_W[64+12d+3k+s, j], scales=[1,4/3,3/4].
// Wt layout: float4 (A, Bc, Wz, 0) at [l][d][j].
// std identity: sqrt(max(0.25 m^2, eps)) == max(0.5|m|, 1e-3)  (exact).
// mlp_b2 softmax-invariant -> dropped.
// Perf notes: harness poison-fill of 256MiB ws costs ~40us/iter (untouchable).
// k_score: 2 rules/wave, 6912 waves = 6.75/SIMD for latency hiding (R6: 3.375
// waves/SIMD left k_score latency-bound at ~30us, VALU floor ~8us).

typedef const float* fp;

// workspace layout (floats)
#define WS_WT     0        // 3*64*64*4 = 49152   Wt[l][d][j][c]
#define WS_RELT   49152    // 3*8*12*64 = 18432   relT[l][b][j][d]
#define WS_QW1    67584    // 8*64                query@mlp_W1[64:128]+mlp_b1
#define WS_C2     68096    // 64
#define WS_C2W    68160    // 64                  C2@lin_W1[0:64] + lin_b1
#define WS_P1     68224    // 8*12*64
#define WS_Q3     74368    // 8*12*64
#define WS_Q2     80512    // 8*144*64
#define WS_QW3    154240   // 8*12*64             Q3@lin_W2[0:64] + lin_b2
#define WS_SCORES 160384   // 8*1728
// total 174208 floats = 696832 bytes

__device__ __forceinline__ void acc4f(float q, float rv, float4 wv, float& acc){
  float m = q*rv;
  float p = fmaxf(m, 0.f), n = fminf(m, 0.f);
  acc += p*wv.x;
  acc += n*wv.y;
  acc += fmaxf(0.5f*fabsf(m), 1e-3f)*wv.z;
}

__global__ void k_pre1(fp lin_W, fp query, fp rel_W, fp rel_b, fp mlp_W1,
                       fp mlp_b1, float* ws){
  int t = blockIdx.x*256 + threadIdx.x;
  if (t < 49152){
    // Wt[l][d][j][c]: t = l*16384 + d*256 + j*4 + c  (coalesced writes)
    int c = t & 3; int j = (t>>2)&63; int d = (t>>8)&63; int l = t>>14;
    fp W = lin_W + (size_t)l*832*64 + (64 + 12*d)*64 + j;   // rows stride 64
    float v = 0.f;
    if (c == 0){
      float w0 = W[0] + (4.f/3.f)*W[64]  + 0.75f*W[128];
      float w1 = W[192] + (4.f/3.f)*W[256] + 0.75f*W[320];
      v = 0.5f*w0 + w1;
    } else if (c == 1){
      float w0 = W[0] + (4.f/3.f)*W[64]  + 0.75f*W[128];
      float w2 = W[384] + (4.f/3.f)*W[448] + 0.75f*W[512];
      v = 0.5f*w0 + w2;
    } else if (c == 2){
      v = W[576] + (4.f/3.f)*W[640] + 0.75f*W[704];
    }
    ws[WS_WT + t] = v;
  } else if (t < 67584){
    // relT[l][b][j][d] = (query[b] @ rel_W[l])[j*64+d] + rel_b[l][j*64+d]
    int e = t - 49152;
    int d = e & 63; int j = (e>>6)%12; int b = (e/768)&7; int l = e/6144;
    float acc = rel_b[l*768 + j*64 + d];
    fp W = rel_W + (size_t)l*64*768 + j*64 + d;
    fp q = query + b*64;
    #pragma unroll 8
    for (int k=0;k<64;k++) acc += q[k] * W[k*768];
    ws[WS_RELT + e] = acc;
  } else if (t < 68096){
    int e = t - 67584; int b = e>>6; int j = e&63;
    float acc = mlp_b1[j];
    fp q = query + b*64;
    #pragma unroll 8
    for (int i=0;i<64;i++) acc += q[i] * mlp_W1[(64+i)*64 + j];
    ws[WS_QW1 + e] = acc;
  }
}

// P1 + Q3; C2/C2W computed inline per block (tiny), block 0 publishes C2W.
__global__ void k_pre3(fp indicator, fp lin_W, fp lin_b, float* ws){
  __shared__ float sC2[64], sC2W[64];
  int tid = threadIdx.x;
  if (tid < 64){
    int j = tid;
    float acc = lin_b[j];                          // layer0 bias
    #pragma unroll 8
    for (int d=0; d<64; d++) acc += 1e-3f * ws[WS_WT + ((d<<6)+j)*4 + 2];
    sC2[j] = fmaxf(acc, 0.f);
  }
  __syncthreads();
  if (tid < 64){
    int j = tid;
    float a2 = lin_b[64+j];                        // layer1 bias
    fp W1 = lin_W + 832*64;                        // layer1, rows 0..63
    #pragma unroll 8
    for (int k=0;k<64;k++) a2 += sC2[k] * W1[k*64+j];
    sC2W[j] = a2;
    if (blockIdx.x == 0){ ws[WS_C2 + j] = sC2[j]; ws[WS_C2W + j] = a2; }
  }
  __syncthreads();

  int wave = blockIdx.x*4 + (tid>>6);              // 0..191
  int j = tid & 63;
  bool isP = wave < 96;
  int e = isP ? wave : wave - 96;
  int b = e/12, ii = e%12;
  const float4* W4 = (const float4*)(ws + WS_WT + (isP ? 0 : 16384));
  const float* rel = ws + WS_RELT + (isP ? 0 : 6144) + (b*12+ii)*64;
  float acc = isP ? lin_b[j] : sC2W[j];
  #pragma unroll 4
  for (int d=0; d<64; d++){
    float src = isP ? indicator[d] : sC2[d];
    float4 wv = W4[(d<<6)+j];
    acc4f(src, rel[d], wv, acc);
  }
  float* outp = ws + (isP ? WS_P1 : WS_Q3) + e*64 + j;
  *outp = fmaxf(acc, 0.f);
}

__global__ void k_pre4(fp lin_W, fp lin_b, float* ws){
  int wave = blockIdx.x*4 + (threadIdx.x>>6);      // 0..1247
  int j = threadIdx.x & 63;
  if (wave < 1152){
    int b = wave/144, i0 = (wave/12)%12, i1 = wave%12;
    const float4* pv   = (const float4*)(ws + WS_P1 + (b*12+i0)*64);
    const float4* relv = (const float4*)(ws + WS_RELT + 6144 + (b*12+i1)*64);
    const float4* W4j  = (const float4*)(ws + WS_WT + 16384) + j;
    float acc = ws[WS_C2W + j];
    #pragma unroll 4
    for (int dc=0; dc<16; dc++){
      float4 rv = relv[dc];
      float4 p  = pv[dc];
      float4 w0 = W4j[(4*dc+0)*64];
      float4 w1 = W4j[(4*dc+1)*64];
      float4 w2 = W4j[(4*dc+2)*64];
      float4 w3 = W4j[(4*dc+3)*64];
      acc4f(p.x, rv.x, w0, acc);
      acc4f(p.y, rv.y, w1, acc);
      acc4f(p.z, rv.z, w2, acc);
      acc4f(p.w, rv.w, w3, acc);
    }
    ws[WS_Q2 + wave*64 + j] = fmaxf(acc, 0.f);
  } else if (wave < 1248){
    int e = wave - 1152;
    const float* q = ws + WS_Q3 + e*64;
    fp W2 = lin_W + 2*832*64;                      // layer2, rows 0..63
    float acc = lin_b[128 + j];
    #pragma unroll 8
    for (int k=0;k<64;k++) acc += q[k]*W2[k*64+j];
    ws[WS_QW3 + e*64 + j] = acc;
  }
}

// one wave = 2 rules sharing (b,i0,i2), i1 in {i1b,i1b+1}.
// 6912 waves (= 6.75/SIMD) for latency hiding; Wt2 loads reused 2x in-wave.
__global__ __launch_bounds__(256, 4) void k_score(fp mlp_W1, fp mlp_W2, float* ws){
  __shared__ float fin[4][2][64];
  int w = threadIdx.x >> 6;
  int j = threadIdx.x & 63;
  int wave = blockIdx.x*4 + w;                 // 0..6911
  int b = wave/864; int rem = wave%864;
  int i0 = rem/72; int t72 = rem%72;
  int i2 = t72/6;  int i1b = (t72%6)*2;
  const float4* W4j  = (const float4*)(ws + WS_WT + 32768) + j;
  const float4* relv = (const float4*)(ws + WS_RELT + 12288 + (b*12+i2)*64);
  const float* q2base = ws + WS_Q2 + ((b*12+i0)*12 + i1b)*64;
  const float4* q0v = (const float4*)(q2base);
  const float4* q1v = (const float4*)(q2base + 64);
  float a0 = ws[WS_QW3 + (b*12+i2)*64 + j];
  float acc0=a0, acc1=a0;
  #pragma unroll 4
  for (int dc=0; dc<16; dc++){
    float4 rv = relv[dc];
    float4 qa = q0v[dc], qb = q1v[dc];
    float4 w0 = W4j[(4*dc+0)*64];
    float4 w1 = W4j[(4*dc+1)*64];
    float4 w2 = W4j[(4*dc+2)*64];
    float4 w3 = W4j[(4*dc+3)*64];
    acc4f(qa.x, rv.x, w0, acc0); acc4f(qb.x, rv.x, w0, acc1);
    acc4f(qa.y, rv.y, w1, acc0); acc4f(qb.y, rv.y, w1, acc1);
    acc4f(qa.z, rv.z, w2, acc0); acc4f(qb.z, rv.z, w2, acc1);
    acc4f(qa.w, rv.w, w3, acc0); acc4f(qb.w, rv.w, w3, acc1);
  }
  fin[w][0][j]=fmaxf(acc0,0.f); fin[w][1][j]=fmaxf(acc1,0.f);
  __syncthreads();
  float qw = ws[WS_QW1 + b*64 + j];
  float w2v = mlp_W2[j];
  float h0 = qw, h1 = qw;
  const float* f0 = fin[w][0];
  const float* f1 = fin[w][1];
  #pragma unroll 8
  for (int i=0;i<64;i++){
    float w1 = mlp_W1[i*64+j];                     // rows 0..63, shared by both
    h0 += f0[i]*w1;
    h1 += f1[i]*w1;
  }
  float s0 = fmaxf(h0, 0.f) * w2v;
  float s1 = fmaxf(h1, 0.f) * w2v;
  #pragma unroll
  for (int off=32; off>0; off>>=1){
    s0 += __shfl_down(s0, off, 64);
    s1 += __shfl_down(s1, off, 64);
  }
  if (j == 0){
    int rbase = i0*144 + i1b*12 + i2;
    ws[WS_SCORES + b*1728 + rbase]      = s0;  // mlp_b2 dropped (softmax-inv)
    ws[WS_SCORES + b*1728 + rbase + 12] = s1;
  }
}

__global__ void k_final(fp relation_emb, float* ws, float* out){
  int b = blockIdx.x, tid = threadIdx.x;           // 256 threads
  __shared__ float se[1728];
  __shared__ float red[256];
  __shared__ float bins[36];
  const float* sc = ws + WS_SCORES + b*1728;
  float mx = -1e30f;
  for (int r=tid; r<1728; r+=256){ float v = sc[r]; se[r] = v; mx = fmaxf(mx, v); }
  red[tid] = mx; __syncthreads();
  for (int s=128; s>0; s>>=1){ if (tid<s) red[tid] = fmaxf(red[tid], red[tid+s]); __syncthreads(); }
  mx = red[0]; __syncthreads();
  float ts = 0.f;
  for (int r=tid; r<1728; r+=256){ float e = expf(se[r]-mx); se[r] = e; ts += e; }
  red[tid] = ts; __syncthreads();
  for (int s=128; s>0; s>>=1){ if (tid<s) red[tid] += red[tid+s]; __syncthreads(); }
  float tot = red[0]; __syncthreads();
  if (tid < 36){
    int h = tid/12, jj = tid%12;
    float a = 0.f;
    if (h == 0){
      const float* p = se + jj*144;
      for (int k=0;k<144;k++) a += p[k];
    } else if (h == 1){
      for (int i0=0;i0<12;i0++){
        const float* p = se + i0*144 + jj*12;
        for (int i2=0;i2<12;i2++) a += p[i2];
      }
    } else {
      for (int i0=0;i0<12;i0++)
        for (int i1=0;i1<12;i1++) a += se[i0*144 + i1*12 + jj];
    }
    bins[tid] = a;
  }
  __syncthreads();
  if (tid < 192){
    int h = tid>>6, d = tid&63;
    float acc = 0.f;
    #pragma unroll
    for (int jj=0; jj<12; jj++) acc += bins[h*12+jj] * relation_emb[jj*64+d];
    out[b*192 + tid] = acc/tot;                    // subgoals, f32
  }
  if (tid >= 192 && tid < 195){
    out[1536 + b*3 + (tid-192)] = 1.0f;            // masks = True, f32
  }
}

extern "C" void kernel_launch(void* const* d_in, const int* in_sizes, int n_in,
                              void* d_out, int out_size, void* d_ws, size_t ws_size,
                              hipStream_t stream){
  fp query        = (fp)d_in[0];
  fp relation_emb = (fp)d_in[1];
  fp indicator    = (fp)d_in[2];
  fp rel_W        = (fp)d_in[3];
  fp rel_b        = (fp)d_in[4];
  fp lin_W        = (fp)d_in[5];
  fp lin_b        = (fp)d_in[6];
  fp mlp_W1       = (fp)d_in[7];
  fp mlp_b1       = (fp)d_in[8];
  fp mlp_W2       = (fp)d_in[9];
  float* ws = (float*)d_ws;
  float* out = (float*)d_out;

  k_pre1 <<<266,  256, 0, stream>>>(lin_W, query, rel_W, rel_b, mlp_W1, mlp_b1, ws);
  k_pre3 <<<48,   256, 0, stream>>>(indicator, lin_W, lin_b, ws);
  k_pre4 <<<312,  256, 0, stream>>>(lin_W, lin_b, ws);
  k_score<<<1728, 256, 0, stream>>>(mlp_W1, mlp_W2, ws);
  k_final<<<8,    256, 0, stream>>>(relation_emb, ws, out);
}

// Round 9
// 124.817 us; speedup vs baseline: 1.1856x; 1.0960x over previous
//
#include <hip/hip_runtime.h>
#include <hip/hip_bf16.h>

// RuleNBFNet: B=8, D=64, H=3, R2=12, Rn=1728.  Inputs f32, output f32.
// 4-kernel pipeline: k_pre1 (Wt,relT,QW1) -> k_mid (Q2,QW3; in-block C2/C2W/P1)
// -> k_score (LDS-staged Wt2, 4 rules/wave, scores out) -> k_final (softmax+emb).
// Feature algebra: m=q*rel, p=max(m,0), n=min(m,0):
//   0.5m*W0 + p*W1 + n*W2 + max(0.5|m|,1e-3)*W3 = p*A + n*Bc + max(.5|m|,1e-3)*Wz
// Wt float4 (A,Bc,Wz,0) at [l][d][j]; scales_tail=[1,4/3,3/4] folded.
// std identity: sqrt(max(0.25m^2,eps)) == max(0.5|m|,1e-3) (exact).
// mlp_b2 softmax-invariant -> dropped.
// R8 lesson: fused cross-block float-atomic bins + ordinary-load readback
// produced uniform-attention corruption (G16: per-XCD coherence) -> reverted
// to separate k_final (bit-exact verified R5-R7). LDS-staged Wt2 kept: breaks
// the weight-L2-BW <-> occupancy tradeoff found in R7.

typedef const float* fp;

// workspace layout (floats)
#define WS_WT     0        // 3*64*64*4 = 49152   Wt[l][d][j][c]
#define WS_RELT   49152    // 3*8*12*64 = 18432   relT[l][b][j][d]
#define WS_QW1    67584    // 8*64                query@mlp_W1[64:128]+mlp_b1
#define WS_Q2     68096    // 8*144*64 = 73728
#define WS_QW3    141824   // 8*12*64             Q3@lin_W2[0:64] + lin_b2
#define WS_SCORES 142592   // 8*1728
// total 156416 floats

__device__ __forceinline__ void acc4f(float q, float rv, float4 wv, float& acc){
  float m = q*rv;
  float p = fmaxf(m, 0.f), n = fminf(m, 0.f);
  acc += p*wv.x;
  acc += n*wv.y;
  acc += fmaxf(0.5f*fabsf(m), 1e-3f)*wv.z;
}

__global__ void k_pre1(fp lin_W, fp query, fp rel_W, fp rel_b, fp mlp_W1,
                       fp mlp_b1, float* ws){
  int t = blockIdx.x*256 + threadIdx.x;
  if (t < 49152){
    // Wt[l][d][j][c]: t = l*16384 + d*256 + j*4 + c  (coalesced writes)
    int c = t & 3; int j = (t>>2)&63; int d = (t>>8)&63; int l = t>>14;
    fp W = lin_W + (size_t)l*832*64 + (64 + 12*d)*64 + j;   // rows stride 64
    float v = 0.f;
    if (c == 0){
      float w0 = W[0] + (4.f/3.f)*W[64]  + 0.75f*W[128];
      float w1 = W[192] + (4.f/3.f)*W[256] + 0.75f*W[320];
      v = 0.5f*w0 + w1;
    } else if (c == 1){
      float w0 = W[0] + (4.f/3.f)*W[64]  + 0.75f*W[128];
      float w2 = W[384] + (4.f/3.f)*W[448] + 0.75f*W[512];
      v = 0.5f*w0 + w2;
    } else if (c == 2){
      v = W[576] + (4.f/3.f)*W[640] + 0.75f*W[704];
    }
    ws[WS_WT + t] = v;
  } else if (t < 67584){
    // relT[l][b][j][d] = (query[b] @ rel_W[l])[j*64+d] + rel_b[l][j*64+d]
    int e = t - 49152;
    int d = e & 63; int j = (e>>6)%12; int b = (e/768)&7; int l = e/6144;
    float acc = rel_b[l*768 + j*64 + d];
    fp W = rel_W + (size_t)l*64*768 + j*64 + d;
    fp q = query + b*64;
    #pragma unroll 8
    for (int k=0;k<64;k++) acc += q[k] * W[k*768];
    ws[WS_RELT + e] = acc;
  } else if (t < 68096){
    int e = t - 67584; int b = e>>6; int j = e&63;
    float acc = mlp_b1[j];
    fp q = query + b*64;
    #pragma unroll 8
    for (int i=0;i<64;i++) acc += q[i] * mlp_W1[(64+i)*64 + j];
    ws[WS_QW1 + e] = acc;
  }
}

// blocks 0..95: (b,i0) -> Q2[b,i0,0..11]; blocks 96..103: b -> QW3[b,0..11]
__global__ void k_mid(fp indicator, fp lin_W, fp lin_b, float* ws){
  __shared__ float sC2[64], sC2W[64], sP1[64], sQ3[12][64];
  int tid = threadIdx.x;                    // 768 threads = 12 waves
  int w = tid>>6, j = tid&63;
  bool isQ2 = blockIdx.x < 96;
  int b  = isQ2 ? blockIdx.x/12 : blockIdx.x-96;
  int i0 = isQ2 ? blockIdx.x%12 : 0;
  if (w == 0){
    float acc = lin_b[j];                   // C2: layer0 const state
    #pragma unroll 8
    for (int d=0; d<64; d++) acc += 1e-3f * ws[WS_WT + ((d<<6)+j)*4 + 2];
    sC2[j] = fmaxf(acc, 0.f);
  } else if (w == 1 && isQ2){
    const float4* W4 = (const float4*)(ws + WS_WT);        // layer0 Wt
    const float* rel = ws + WS_RELT + (b*12+i0)*64;        // l=0
    float acc = lin_b[j];
    #pragma unroll 4
    for (int d=0; d<64; d++) acc4f(indicator[d], rel[d], W4[(d<<6)+j], acc);
    sP1[j] = fmaxf(acc, 0.f);
  }
  __syncthreads();
  if (w == 0){
    float a2 = lin_b[64+j];                 // C2W = C2 @ lin_W1[0:64] + b1
    fp W1 = lin_W + 832*64;
    #pragma unroll 8
    for (int k=0;k<64;k++) a2 += sC2[k] * W1[k*64+j];
    sC2W[j] = a2;
  }
  __syncthreads();
  const float4* W4 = (const float4*)(ws + WS_WT + 16384);  // layer1 Wt
  const float* rel = ws + WS_RELT + 6144 + (b*12+w)*64;    // l=1, idx=w
  if (isQ2){
    float acc = sC2W[j];
    #pragma unroll 4
    for (int d=0; d<64; d++) acc4f(sP1[d], rel[d], W4[(d<<6)+j], acc);
    ws[WS_Q2 + ((b*12+i0)*12+w)*64 + j] = fmaxf(acc, 0.f);
  } else {
    float acc = sC2W[j];
    #pragma unroll 4
    for (int d=0; d<64; d++) acc4f(sC2[d], rel[d], W4[(d<<6)+j], acc);
    sQ3[w][j] = fmaxf(acc, 0.f);
    __syncthreads();                        // block-uniform branch
    fp W2 = lin_W + 2*832*64;               // layer2, rows 0..63
    float a = lin_b[128+j];
    #pragma unroll 8
    for (int k=0;k<64;k++) a += sQ3[w][k]*W2[k*64+j];
    ws[WS_QW3 + (b*12+w)*64 + j] = a;
  }
}

// 864 blocks x 256 thr; wave = 4 rules (b,i0,i2 shared, i1 = i1b..i1b+3).
// Wt2 staged through LDS in 4x16KB chunks (27MB L2 traffic vs 221MB direct).
__global__ __launch_bounds__(256) void k_score(fp mlp_W1, fp mlp_W2, float* ws){
  __shared__ float wt_s[4096];              // 16 KB chunk
  __shared__ float fin[4][4][64];
  int tid = threadIdx.x, w = tid>>6, j = tid&63;
  int wave = blockIdx.x*4 + w;              // 0..3455
  int b = blockIdx.x/108;                   // block-uniform (432 waves/b)
  int rem = wave%432;
  int i0 = rem/36; int t36 = rem%36;
  int i2 = t36/3;  int i1b = (t36%3)*4;
  const float4* relv = (const float4*)(ws + WS_RELT + 12288 + (b*12+i2)*64);
  const float* q2base = ws + WS_Q2 + ((b*12+i0)*12 + i1b)*64;
  const float4* q0v = (const float4*)(q2base);
  const float4* q1v = (const float4*)(q2base + 64);
  const float4* q2v = (const float4*)(q2base + 128);
  const float4* q3v = (const float4*)(q2base + 192);
  float a0 = ws[WS_QW3 + (b*12+i2)*64 + j];
  float acc0=a0, acc1=a0, acc2=a0, acc3=a0;
  const float4* Wt2 = (const float4*)(ws + WS_WT + 32768);
  for (int ch=0; ch<4; ch++){
    __syncthreads();                        // protect previous chunk
    {
      const float4* src = Wt2 + ch*1024;
      float4* dst = (float4*)wt_s;
      #pragma unroll
      for (int k=0; k<4; k++) dst[tid + k*256] = src[tid + k*256];
    }
    __syncthreads();
    #pragma unroll
    for (int dq=0; dq<4; dq++){
      int dc = ch*4 + dq;
      float4 rv = relv[dc];
      float4 qa = q0v[dc], qb = q1v[dc], qc = q2v[dc], qd = q3v[dc];
      const float4* wl = (const float4*)wt_s + dq*256 + j;
      float4 w0 = wl[0], w1 = wl[64], w2 = wl[128], w3 = wl[192];
      acc4f(qa.x, rv.x, w0, acc0); acc4f(qb.x, rv.x, w0, acc1);
      acc4f(qc.x, rv.x, w0, acc2); acc4f(qd.x, rv.x, w0, acc3);
      acc4f(qa.y, rv.y, w1, acc0); acc4f(qb.y, rv.y, w1, acc1);
      acc4f(qc.y, rv.y, w1, acc2); acc4f(qd.y, rv.y, w1, acc3);
      acc4f(qa.z, rv.z, w2, acc0); acc4f(qb.z, rv.z, w2, acc1);
      acc4f(qc.z, rv.z, w2, acc2); acc4f(qd.z, rv.z, w2, acc3);
      acc4f(qa.w, rv.w, w3, acc0); acc4f(qb.w, rv.w, w3, acc1);
      acc4f(qc.w, rv.w, w3, acc2); acc4f(qd.w, rv.w, w3, acc3);
    }
  }
  __syncthreads();
  fin[w][0][j]=fmaxf(acc0,0.f); fin[w][1][j]=fmaxf(acc1,0.f);
  fin[w][2][j]=fmaxf(acc2,0.f); fin[w][3][j]=fmaxf(acc3,0.f);
  __syncthreads();
  float qw = ws[WS_QW1 + b*64 + j];
  float w2v = mlp_W2[j];
  float h0=qw, h1=qw, h2=qw, h3=qw;
  #pragma unroll 8
  for (int i=0;i<64;i++){
    float wv = mlp_W1[i*64+j];              // rows 0..63, shared by 4 rules
    h0 += fin[w][0][i]*wv; h1 += fin[w][1][i]*wv;
    h2 += fin[w][2][i]*wv; h3 += fin[w][3][i]*wv;
  }
  float s0=fmaxf(h0,0.f)*w2v, s1=fmaxf(h1,0.f)*w2v;
  float s2=fmaxf(h2,0.f)*w2v, s3=fmaxf(h3,0.f)*w2v;
  #pragma unroll
  for (int off=32; off>0; off>>=1){
    s0 += __shfl_down(s0, off, 64); s1 += __shfl_down(s1, off, 64);
    s2 += __shfl_down(s2, off, 64); s3 += __shfl_down(s3, off, 64);
  }
  if (j == 0){
    int rbase = i0*144 + i1b*12 + i2;
    float* S = ws + WS_SCORES + b*1728 + rbase;
    S[0] = s0; S[12] = s1; S[24] = s2; S[36] = s3;
  }
}

__global__ void k_final(fp relation_emb, float* ws, float* out){
  int b = blockIdx.x, tid = threadIdx.x;           // 256 threads
  __shared__ float se[1728];
  __shared__ float red[256];
  __shared__ float bins[36];
  const float* sc = ws + WS_SCORES + b*1728;
  float mx = -1e30f;
  for (int r=tid; r<1728; r+=256){ float v = sc[r]; se[r] = v; mx = fmaxf(mx, v); }
  red[tid] = mx; __syncthreads();
  for (int s=128; s>0; s>>=1){ if (tid<s) red[tid] = fmaxf(red[tid], red[tid+s]); __syncthreads(); }
  mx = red[0]; __syncthreads();
  float ts = 0.f;
  for (int r=tid; r<1728; r+=256){ float e = expf(se[r]-mx); se[r] = e; ts += e; }
  red[tid] = ts; __syncthreads();
  for (int s=128; s>0; s>>=1){ if (tid<s) red[tid] += red[tid+s]; __syncthreads(); }
  float tot = red[0]; __syncthreads();
  if (tid < 36){
    int h = tid/12, jj = tid%12;
    float a = 0.f;
    if (h == 0){
      const float* p = se + jj*144;
      for (int k=0;k<144;k++) a += p[k];
    } else if (h == 1){
      for (int i0=0;i0<12;i0++){
        const float* p = se + i0*144 + jj*12;
        for (int i2=0;i2<12;i2++) a += p[i2];
      }
    } else {
      for (int i0=0;i0<12;i0++)
        for (int i1=0;i1<12;i1++) a += se[i0*144 + i1*12 + jj];
    }
    bins[tid] = a;
  }
  __syncthreads();
  if (tid < 192){
    int h = tid>>6, d = tid&63;
    float acc = 0.f;
    #pragma unroll
    for (int jj=0; jj<12; jj++) acc += bins[h*12+jj] * relation_emb[jj*64+d];
    out[b*192 + tid] = acc/tot;                    // subgoals, f32
  }
  if (tid >= 192 && tid < 195){
    out[1536 + b*3 + (tid-192)] = 1.0f;            // masks = True, f32
  }
}

extern "C" void kernel_launch(void* const* d_in, const int* in_sizes, int n_in,
                              void* d_out, int out_size, void* d_ws, size_t ws_size,
                              hipStream_t stream){
  fp query        = (fp)d_in[0];
  fp relation_emb = (fp)d_in[1];
  fp indicator    = (fp)d_in[2];
  fp rel_W        = (fp)d_in[3];
  fp rel_b        = (fp)d_in[4];
  fp lin_W        = (fp)d_in[5];
  fp lin_b        = (fp)d_in[6];
  fp mlp_W1       = (fp)d_in[7];
  fp mlp_b1       = (fp)d_in[8];
  fp mlp_W2       = (fp)d_in[9];
  float* ws = (float*)d_ws;
  float* out = (float*)d_out;

  k_pre1 <<<266, 256, 0, stream>>>(lin_W, query, rel_W, rel_b, mlp_W1, mlp_b1, ws);
  k_mid  <<<104, 768, 0, stream>>>(indicator, lin_W, lin_b, ws);
  k_score<<<864, 256, 0, stream>>>(mlp_W1, mlp_W2, ws);
  k_final<<<8,   256, 0, stream>>>(relation_emb, ws, out);
}